// Round 1
// baseline (72.326 us; speedup 1.0000x reference)
//
#include <hip/hip_runtime.h>

#define BINS 256
#define NCOPY 4           // one private LDS histogram copy per wave (256 thr = 4 waves)
#define BLOCK 256

// Pass 1: build exact integer histograms of both images in one read pass.
__global__ __launch_bounds__(BLOCK) void hist_kernel(
    const float* __restrict__ img1, const float* __restrict__ img2,
    unsigned int* __restrict__ g_h1, unsigned int* __restrict__ g_h2,
    long long n)    // total elements per image
{
    __shared__ unsigned int lh[2][NCOPY][BINS];

    const int tid  = threadIdx.x;
    const int wave = tid >> 6;

    // zero LDS histograms
    for (int i = tid; i < 2 * NCOPY * BINS; i += BLOCK)
        ((unsigned int*)lh)[i] = 0u;
    __syncthreads();

    const long long n4     = n >> 2;                      // float4 count
    const long long stride = (long long)gridDim.x * BLOCK;
    const float4* p1 = (const float4*)img1;
    const float4* p2 = (const float4*)img2;

    for (long long i = (long long)blockIdx.x * BLOCK + tid; i < n4; i += stride) {
        float4 a = p1[i];
        float4 b = p2[i];
        const float* av = &a.x;
        const float* bv = &b.x;
#pragma unroll
        for (int j = 0; j < 4; ++j) {
            float x = av[j];
            if (x >= 0.0f && x <= 1.0f) {
                // exact match to JAX: clip(floor(x*256), 0, 255); x>=0 => floor>=0
                int bin = (int)floorf(x * 256.0f);
                bin = bin > 255 ? 255 : bin;
                atomicAdd(&lh[0][wave][bin], 1u);
            }
            float y = bv[j];
            if (y >= 0.0f && y <= 1.0f) {
                int bin = (int)floorf(y * 256.0f);
                bin = bin > 255 ? 255 : bin;
                atomicAdd(&lh[1][wave][bin], 1u);
            }
        }
    }

    // scalar tail (n % 4), handled by block 0 only
    if (blockIdx.x == 0) {
        for (long long i = (n4 << 2) + tid; i < n; i += BLOCK) {
            float x = img1[i];
            if (x >= 0.0f && x <= 1.0f) {
                int bin = (int)floorf(x * 256.0f);
                bin = bin > 255 ? 255 : bin;
                atomicAdd(&lh[0][wave][bin], 1u);
            }
            float y = img2[i];
            if (y >= 0.0f && y <= 1.0f) {
                int bin = (int)floorf(y * 256.0f);
                bin = bin > 255 ? 255 : bin;
                atomicAdd(&lh[1][wave][bin], 1u);
            }
        }
    }

    __syncthreads();

    // reduce the per-wave copies and flush to global (device-scope atomics)
    for (int b = tid; b < BINS; b += BLOCK) {
        unsigned int s1 = 0u, s2 = 0u;
#pragma unroll
        for (int c = 0; c < NCOPY; ++c) { s1 += lh[0][c][b]; s2 += lh[1][c][b]; }
        if (s1) atomicAdd(&g_h1[b], s1);
        if (s2) atomicAdd(&g_h2[b], s2);
    }
}

// Pass 2: loss = sum_i |c1[i]/N1 - c2[i]/N2| / 256, in double precision.
__global__ __launch_bounds__(BINS) void finalize_kernel(
    const unsigned int* __restrict__ h1, const unsigned int* __restrict__ h2,
    float* __restrict__ out)
{
    const int tid = threadIdx.x;          // one thread per bin
    const unsigned int c1 = h1[tid];
    const unsigned int c2 = h2[tid];

    __shared__ unsigned int s1[4], s2[4];
    __shared__ double sd[4];

    // wave-reduce the total counts (64-lane waves)
    unsigned int r1 = c1, r2 = c2;
#pragma unroll
    for (int off = 32; off > 0; off >>= 1) {
        r1 += __shfl_down(r1, off);
        r2 += __shfl_down(r2, off);
    }
    if ((tid & 63) == 0) { s1[tid >> 6] = r1; s2[tid >> 6] = r2; }
    __syncthreads();

    const double N1 = (double)(s1[0] + s1[1] + s1[2] + s1[3]);
    const double N2 = (double)(s2[0] + s2[1] + s2[2] + s2[3]);

    double d = fabs((double)c1 / N1 - (double)c2 / N2);
#pragma unroll
    for (int off = 32; off > 0; off >>= 1)
        d += __shfl_down(d, off);
    if ((tid & 63) == 0) sd[tid >> 6] = d;
    __syncthreads();

    if (tid == 0) {
        double tot = sd[0] + sd[1] + sd[2] + sd[3];
        out[0] = (float)(tot / (double)BINS);
    }
}

extern "C" void kernel_launch(void* const* d_in, const int* in_sizes, int n_in,
                              void* d_out, int out_size, void* d_ws, size_t ws_size,
                              hipStream_t stream) {
    const float* img1 = (const float*)d_in[0];
    const float* img2 = (const float*)d_in[1];
    const long long n = (long long)in_sizes[0];   // elements per image (same for both)

    unsigned int* g_h1 = (unsigned int*)d_ws;
    unsigned int* g_h2 = g_h1 + BINS;

    // zero the global histograms (ws is poisoned / left dirty between calls)
    hipMemsetAsync(d_ws, 0, 2 * BINS * sizeof(unsigned int), stream);

    const long long n4 = n >> 2;
    int blocks = (int)((n4 + BLOCK - 1) / BLOCK);
    if (blocks > 2048) blocks = 2048;
    if (blocks < 1) blocks = 1;

    hist_kernel<<<blocks, BLOCK, 0, stream>>>(img1, img2, g_h1, g_h2, n);
    finalize_kernel<<<1, BINS, 0, stream>>>(g_h1, g_h2, (float*)d_out);
}

// Round 2
// 68.549 us; speedup vs baseline: 1.0551x; 1.0551x over previous
//
#include <hip/hip_runtime.h>

#define BINS 256
#define NCOPY 16          // bank-spread copies, indexed by lane&15
#define BLOCK 256

// Pass 1: build exact integer histograms of both images in one read pass.
// LDS layout lh[img][bin][copy]: word addr = bin*16 + (lane&15)
//   -> bank = 16*(bin&1) + (lane&15): wave's 64 lanes spread ~2/bank (free),
//      same-address collision needs same (lane&15) AND same bin (~1/256).
__global__ __launch_bounds__(BLOCK) void hist_kernel(
    const float* __restrict__ img1, const float* __restrict__ img2,
    unsigned int* __restrict__ g_h1, unsigned int* __restrict__ g_h2,
    long long n)    // total elements per image
{
    __shared__ unsigned int lh[2][BINS][NCOPY];

    const int tid  = threadIdx.x;
    const int copy = tid & (NCOPY - 1);

    // zero LDS histograms (2*256*16 = 8192 words, 32 per thread)
    for (int i = tid; i < 2 * BINS * NCOPY; i += BLOCK)
        ((unsigned int*)lh)[i] = 0u;
    __syncthreads();

    const long long n4     = n >> 2;                      // float4 count
    const long long stride = (long long)gridDim.x * BLOCK;
    const float4* p1 = (const float4*)img1;
    const float4* p2 = (const float4*)img2;

    unsigned int* h1c = &lh[0][0][copy];
    unsigned int* h2c = &lh[1][0][copy];

    for (long long i = (long long)blockIdx.x * BLOCK + tid; i < n4; i += 2 * stride) {
        // issue up to 4 independent float4 loads before the atomic burst
        float4 a0 = p1[i];
        float4 b0 = p2[i];
        const long long i1 = i + stride;
        const bool have1 = (i1 < n4);
        float4 a1, b1;
        if (have1) { a1 = p1[i1]; b1 = p2[i1]; }

        {
            const float* av = &a0.x;
            const float* bv = &b0.x;
#pragma unroll
            for (int j = 0; j < 4; ++j) {
                float x = av[j];
                if (x >= 0.0f && x <= 1.0f) {
                    int bin = (int)floorf(x * 256.0f);
                    bin = bin > 255 ? 255 : bin;
                    atomicAdd(&h1c[bin * NCOPY], 1u);
                }
                float y = bv[j];
                if (y >= 0.0f && y <= 1.0f) {
                    int bin = (int)floorf(y * 256.0f);
                    bin = bin > 255 ? 255 : bin;
                    atomicAdd(&h2c[bin * NCOPY], 1u);
                }
            }
        }
        if (have1) {
            const float* av = &a1.x;
            const float* bv = &b1.x;
#pragma unroll
            for (int j = 0; j < 4; ++j) {
                float x = av[j];
                if (x >= 0.0f && x <= 1.0f) {
                    int bin = (int)floorf(x * 256.0f);
                    bin = bin > 255 ? 255 : bin;
                    atomicAdd(&h1c[bin * NCOPY], 1u);
                }
                float y = bv[j];
                if (y >= 0.0f && y <= 1.0f) {
                    int bin = (int)floorf(y * 256.0f);
                    bin = bin > 255 ? 255 : bin;
                    atomicAdd(&h2c[bin * NCOPY], 1u);
                }
            }
        }
    }

    // scalar tail (n % 4), handled by block 0 only
    if (blockIdx.x == 0) {
        for (long long i = (n4 << 2) + tid; i < n; i += BLOCK) {
            float x = img1[i];
            if (x >= 0.0f && x <= 1.0f) {
                int bin = (int)floorf(x * 256.0f);
                bin = bin > 255 ? 255 : bin;
                atomicAdd(&h1c[bin * NCOPY], 1u);
            }
            float y = img2[i];
            if (y >= 0.0f && y <= 1.0f) {
                int bin = (int)floorf(y * 256.0f);
                bin = bin > 255 ? 255 : bin;
                atomicAdd(&h2c[bin * NCOPY], 1u);
            }
        }
    }

    __syncthreads();

    // reduce the copies and flush to global (device-scope atomics)
    for (int b = tid; b < BINS; b += BLOCK) {
        unsigned int s1 = 0u, s2 = 0u;
#pragma unroll
        for (int c = 0; c < NCOPY; ++c) { s1 += lh[0][b][c]; s2 += lh[1][b][c]; }
        if (s1) atomicAdd(&g_h1[b], s1);
        if (s2) atomicAdd(&g_h2[b], s2);
    }
}

// Pass 2: loss = sum_i |c1[i]/N1 - c2[i]/N2| / 256, in double precision.
__global__ __launch_bounds__(BINS) void finalize_kernel(
    const unsigned int* __restrict__ h1, const unsigned int* __restrict__ h2,
    float* __restrict__ out)
{
    const int tid = threadIdx.x;          // one thread per bin
    const unsigned int c1 = h1[tid];
    const unsigned int c2 = h2[tid];

    __shared__ unsigned int s1[4], s2[4];
    __shared__ double sd[4];

    unsigned int r1 = c1, r2 = c2;
#pragma unroll
    for (int off = 32; off > 0; off >>= 1) {
        r1 += __shfl_down(r1, off);
        r2 += __shfl_down(r2, off);
    }
    if ((tid & 63) == 0) { s1[tid >> 6] = r1; s2[tid >> 6] = r2; }
    __syncthreads();

    const double N1 = (double)(s1[0] + s1[1] + s1[2] + s1[3]);
    const double N2 = (double)(s2[0] + s2[1] + s2[2] + s2[3]);

    double d = fabs((double)c1 / N1 - (double)c2 / N2);
#pragma unroll
    for (int off = 32; off > 0; off >>= 1)
        d += __shfl_down(d, off);
    if ((tid & 63) == 0) sd[tid >> 6] = d;
    __syncthreads();

    if (tid == 0) {
        double tot = sd[0] + sd[1] + sd[2] + sd[3];
        out[0] = (float)(tot / (double)BINS);
    }
}

extern "C" void kernel_launch(void* const* d_in, const int* in_sizes, int n_in,
                              void* d_out, int out_size, void* d_ws, size_t ws_size,
                              hipStream_t stream) {
    const float* img1 = (const float*)d_in[0];
    const float* img2 = (const float*)d_in[1];
    const long long n = (long long)in_sizes[0];   // elements per image (same for both)

    unsigned int* g_h1 = (unsigned int*)d_ws;
    unsigned int* g_h2 = g_h1 + BINS;

    // zero the global histograms (ws is poisoned / left dirty between calls)
    hipMemsetAsync(d_ws, 0, 2 * BINS * sizeof(unsigned int), stream);

    const long long n4 = n >> 2;
    int blocks = (int)((n4 + BLOCK - 1) / BLOCK);
    if (blocks > 2048) blocks = 2048;
    if (blocks < 1) blocks = 1;

    hist_kernel<<<blocks, BLOCK, 0, stream>>>(img1, img2, g_h1, g_h2, n);
    finalize_kernel<<<1, BINS, 0, stream>>>(g_h1, g_h2, (float*)d_out);
}